// Round 2
// baseline (128.182 us; speedup 1.0000x reference)
//
#include <hip/hip_runtime.h>
#include <math.h>

#define A_N      5
#define GRID_HW  52
#define NCLS     80
#define CH       85
#define SCORE_T  0.15f
#define IOU_T    0.5f
#define NEGV     (-1e9f)
#define MAXOUT   10

#define BPB          64                 // boxes per decode block
#define DEC_THREADS  256                // 4 lanes per box
#define TILE_FLOATS  (BPB * CH)         // 5440 floats = 21,760 B LDS
#define TILE_F4      (TILE_FLOATS / 4)  // 1360 float4 loads per tile
#define NMS_MMAX     2800               // LDS-resident NMS capacity (56 KB)

// ---------------------------------------------------------------------------
// Decode: one block = 64 boxes. Stage the tile (contiguous 21.76 KB) into LDS
// with coalesced float4 loads, then 4 lanes cooperate per box (20 class
// logits each) and merge max/argmax/sumexp with 2 shfl_xor rounds.
// ---------------------------------------------------------------------------
__global__ __launch_bounds__(DEC_THREADS) void decode_kernel(
    const float* __restrict__ preds,
    const float* __restrict__ anchors,
    float* __restrict__ bymin, float* __restrict__ bxmin,
    float* __restrict__ bymax, float* __restrict__ bxmax,
    float* __restrict__ bscore, float* __restrict__ bcls,
    int* __restrict__ counter, int N, int capacity)
{
    __shared__ __align__(16) float lds[TILE_FLOATS];

    const int tile = blockIdx.x;
    const long long tile_f4_base = (long long)tile * TILE_F4;
    const long long total_f4 = ((long long)N * CH) / 4;   // N*CH divisible by 4? guard below
    const float4* src = (const float4*)preds;
    float4* dst = (float4*)lds;

#pragma unroll
    for (int k = 0; k < (TILE_F4 + DEC_THREADS - 1) / DEC_THREADS; ++k) {
        int idx = (int)threadIdx.x + k * DEC_THREADS;
        if (idx < TILE_F4 && (tile_f4_base + idx) < total_f4)
            dst[idx] = src[tile_f4_base + idx];
    }
    __syncthreads();

    const int b = (int)threadIdx.x >> 2;   // box within tile
    const int q = (int)threadIdx.x & 3;    // quarter of the 80 classes
    const int gi = tile * BPB + b;         // global box index
    const float* bp = lds + b * CH;
    const float* cl = bp + 5 + q * 20;

    // pass 1: local max + first-occurrence argmax over 20 logits
    float m = cl[0];
    int   am = q * 20;
#pragma unroll
    for (int j = 1; j < 20; ++j) {
        float x = cl[j];
        if (x > m) { m = x; am = q * 20 + j; }
    }
    // pass 2: local sum of exp(x - m)
    float s = 0.0f;
#pragma unroll
    for (int j = 0; j < 20; ++j) s += expf(cl[j] - m);

    // merge the 4 lanes of this box (xor 1, xor 2 stay inside the 4-group)
#pragma unroll
    for (int off = 1; off <= 2; off <<= 1) {
        float m2 = __shfl_xor(m, off);
        float s2 = __shfl_xor(s, off);
        int   am2 = __shfl_xor(am, off);
        float M = fmaxf(m, m2);
        s = s * expf(m - M) + s2 * expf(m2 - M);
        if (m2 > m || (m2 == m && am2 < am)) am = am2;   // first-max tie-break
        m = M;
    }

    if (q == 0 && gi < N) {
        float conf  = 1.0f / (1.0f + expf(-bp[4]));
        float score = conf / s;              // conf * max softmax prob
        if (score >= SCORE_T) {
            int a = gi % A_N;
            int t = gi / A_N;
            int w = t % GRID_HW;
            int h = (t / GRID_HW) % GRID_HW;
            const float inv = 1.0f / (float)GRID_HW;
            float cx = (1.0f / (1.0f + expf(-bp[0])) + (float)w) * inv;
            float cy = (1.0f / (1.0f + expf(-bp[1])) + (float)h) * inv;
            float bw = expf(bp[2]) * anchors[2 * a]     * inv;
            float bh = expf(bp[3]) * anchors[2 * a + 1] * inv;

            int pos = atomicAdd(counter, 1);
            if (pos < capacity) {
                bymin[pos]  = cy - 0.5f * bh;
                bxmin[pos]  = cx - 0.5f * bw;
                bymax[pos]  = cy + 0.5f * bh;
                bxmax[pos]  = cx + 0.5f * bw;
                bscore[pos] = score;
                bcls[pos]   = (float)am;
            }
        }
    }
}

// ---------------------------------------------------------------------------
// NMS: one wave (64 lanes), wave-synchronous. Scores + packed boxes live in
// LDS when M <= NMS_MMAX (global fallback keeps correctness otherwise).
// 10 iterations of {strided scan + shuffle-butterfly argmax, emit, suppress}.
// ---------------------------------------------------------------------------
__global__ __launch_bounds__(64) void nms_kernel(
    const float* __restrict__ bymin, const float* __restrict__ bxmin,
    const float* __restrict__ bymax, const float* __restrict__ bxmax,
    float* __restrict__ bscore, const float* __restrict__ bcls,
    const int* __restrict__ counter, int capacity,
    float* __restrict__ out)
{
    __shared__ __align__(16) float4 lbox[NMS_MMAX];
    __shared__ float lsc[NMS_MMAX];

    int M = *counter;
    if (M > capacity) M = capacity;
    const bool useLds = (M <= NMS_MMAX);
    const int lane = (int)threadIdx.x;

    if (useLds) {
        for (int j = lane; j < M; j += 64) {
            lbox[j] = make_float4(bymin[j], bxmin[j], bymax[j], bxmax[j]);
            lsc[j]  = bscore[j];
        }
    }
    __syncthreads();

    for (int it = 0; it < MAXOUT; ++it) {
        // strided local argmax (strict > keeps smallest j per lane)
        float bs = -INFINITY;
        int   bi = -1;
        for (int j = lane; j < M; j += 64) {
            float sc = useLds ? lsc[j] : bscore[j];
            if (sc > bs) { bs = sc; bi = j; }
        }
        // butterfly reduce: score desc, index asc tie-break -> all lanes agree
#pragma unroll
        for (int off = 32; off; off >>= 1) {
            float os = __shfl_xor(bs, off);
            int   oi = __shfl_xor(bi, off);
            if (os > bs || (os == bs && oi != -1 && (bi == -1 || oi < bi))) {
                bs = os; bi = oi;
            }
        }

        bool valid = (bi >= 0) && (bs > NEGV * 0.5f);
        float4 box = make_float4(0.f, 0.f, 0.f, 0.f);
        if (valid) {
            box = useLds ? lbox[bi]
                         : make_float4(bymin[bi], bxmin[bi], bymax[bi], bxmax[bi]);
        }

        if (lane == 0) {
            out[it * 6 + 0] = valid ? box.x : 0.0f;
            out[it * 6 + 1] = valid ? box.y : 0.0f;
            out[it * 6 + 2] = valid ? box.z : 0.0f;
            out[it * 6 + 3] = valid ? box.w : 0.0f;
            out[it * 6 + 4] = valid ? bs    : 0.0f;
            out[it * 6 + 5] = valid ? bcls[bi] : 0.0f;
            if (valid) {                       // reference always kills selected
                if (useLds) lsc[bi] = NEGV; else bscore[bi] = NEGV;
            }
        }

        if (valid) {
            float a1 = fmaxf(box.z - box.x, 0.f) * fmaxf(box.w - box.y, 0.f);
            for (int j = lane; j < M; j += 64) {
                float4 bj = useLds ? lbox[j]
                                   : make_float4(bymin[j], bxmin[j], bymax[j], bxmax[j]);
                float ty = fmaxf(box.x, bj.x);
                float tx = fmaxf(box.y, bj.y);
                float by = fminf(box.z, bj.z);
                float bx = fminf(box.w, bj.w);
                float inter = fmaxf(by - ty, 0.f) * fmaxf(bx - tx, 0.f);
                float a2 = fmaxf(bj.z - bj.x, 0.f) * fmaxf(bj.w - bj.y, 0.f);
                float iou = inter / (a1 + a2 - inter + 1e-9f);
                if (iou > IOU_T) {
                    if (useLds) lsc[j] = NEGV; else bscore[j] = NEGV;
                }
            }
        }
        __syncthreads();
    }
}

extern "C" void kernel_launch(void* const* d_in, const int* in_sizes, int n_in,
                              void* d_out, int out_size, void* d_ws, size_t ws_size,
                              hipStream_t stream) {
    (void)n_in; (void)out_size;
    const float* preds   = (const float*)d_in[0];
    const float* anchors = (const float*)d_in[1];
    float* out = (float*)d_out;

    int N = in_sizes[0] / CH;   // 216,320 boxes

    // Workspace: [0,64) counter; then 6 SoA float arrays of `capacity`.
    char* ws = (char*)d_ws;
    int* counter = (int*)ws;
    size_t avail = (ws_size > 64) ? (ws_size - 64) : 0;
    long long cap = (long long)(avail / (6 * sizeof(float)));
    if (cap > N) cap = N;
    if (cap < 0) cap = 0;
    int capacity = (int)cap;

    float* bymin  = (float*)(ws + 64);
    float* bxmin  = bymin  + capacity;
    float* bymax  = bxmin  + capacity;
    float* bxmax  = bymax  + capacity;
    float* bscore = bxmax  + capacity;
    float* bcls   = bscore + capacity;

    hipMemsetAsync(counter, 0, sizeof(int), stream);

    int nTiles = (N + BPB - 1) / BPB;   // 3380 for the bench shape
    decode_kernel<<<nTiles, DEC_THREADS, 0, stream>>>(
        preds, anchors, bymin, bxmin, bymax, bxmax, bscore, bcls,
        counter, N, capacity);
    nms_kernel<<<1, 64, 0, stream>>>(
        bymin, bxmin, bymax, bxmax, bscore, bcls, counter, capacity, out);
}

// Round 3
// 66.887 us; speedup vs baseline: 1.9164x; 1.9164x over previous
//
#include <hip/hip_runtime.h>
#include <math.h>

#define A_N      5
#define GRID_HW  52
#define NCLS     80
#define CH       85
#define SCORE_T  0.15f
#define IOU_T    0.5f
#define NEGV     (-1e9f)
#define MAXOUT   10

#define BPB          64                 // boxes per decode block
#define DEC_THREADS  256                // 4 lanes per box
#define TILE_FLOATS  (BPB * CH)         // 5440 floats = 21,760 B LDS
#define TILE_F4      (TILE_FLOATS / 4)

#define NMS_THREADS  1024
#define NMS_LBOX     8192               // LDS box capacity (128 KB)
#define KA           (NMS_LBOX / NMS_THREADS)   // 8 scores per thread in regs

// ---------------------------------------------------------------------------
// Decode: one block = 64 boxes. Coalesced float4 staging to LDS, 4 lanes/box
// for the 80-class max/argmax/sumexp, shfl merge. Live boxes compacted into
// packed SoA (float4 box, score, class) via atomic counter.
// ---------------------------------------------------------------------------
__global__ __launch_bounds__(DEC_THREADS) void decode_kernel(
    const float* __restrict__ preds,
    const float* __restrict__ anchors,
    float4* __restrict__ pbox, float* __restrict__ pscore,
    float* __restrict__ pcls,
    int* __restrict__ counter, int N, int capacity)
{
    __shared__ __align__(16) float lds[TILE_FLOATS];

    const int tile = blockIdx.x;
    const long long tile_f4_base = (long long)tile * TILE_F4;
    const long long total_f4 = ((long long)N * CH) / 4;
    const float4* src = (const float4*)preds;
    float4* dst = (float4*)lds;

#pragma unroll
    for (int k = 0; k < (TILE_F4 + DEC_THREADS - 1) / DEC_THREADS; ++k) {
        int idx = (int)threadIdx.x + k * DEC_THREADS;
        if (idx < TILE_F4 && (tile_f4_base + idx) < total_f4)
            dst[idx] = src[tile_f4_base + idx];
    }
    __syncthreads();

    const int b = (int)threadIdx.x >> 2;   // box within tile
    const int q = (int)threadIdx.x & 3;    // quarter of the 80 classes
    const int gi = tile * BPB + b;
    const float* bp = lds + b * CH;
    const float* cl = bp + 5 + q * 20;

    float m = cl[0];
    int   am = q * 20;
#pragma unroll
    for (int j = 1; j < 20; ++j) {
        float x = cl[j];
        if (x > m) { m = x; am = q * 20 + j; }
    }
    float s = 0.0f;
#pragma unroll
    for (int j = 0; j < 20; ++j) s += expf(cl[j] - m);

#pragma unroll
    for (int off = 1; off <= 2; off <<= 1) {
        float m2 = __shfl_xor(m, off);
        float s2 = __shfl_xor(s, off);
        int   am2 = __shfl_xor(am, off);
        float M = fmaxf(m, m2);
        s = s * expf(m - M) + s2 * expf(m2 - M);
        if (m2 > m || (m2 == m && am2 < am)) am = am2;   // first-max tie-break
        m = M;
    }

    if (q == 0 && gi < N) {
        float conf  = 1.0f / (1.0f + expf(-bp[4]));
        float score = conf / s;
        if (score >= SCORE_T) {
            int a = gi % A_N;
            int t = gi / A_N;
            int w = t % GRID_HW;
            int h = (t / GRID_HW) % GRID_HW;
            const float inv = 1.0f / (float)GRID_HW;
            float cx = (1.0f / (1.0f + expf(-bp[0])) + (float)w) * inv;
            float cy = (1.0f / (1.0f + expf(-bp[1])) + (float)h) * inv;
            float bw = expf(bp[2]) * anchors[2 * a]     * inv;
            float bh = expf(bp[3]) * anchors[2 * a + 1] * inv;

            int pos = atomicAdd(counter, 1);
            if (pos < capacity) {
                pbox[pos]   = make_float4(cy - 0.5f * bh, cx - 0.5f * bw,
                                          cy + 0.5f * bh, cx + 0.5f * bw);
                pscore[pos] = score;
                pcls[pos]   = (float)am;
            }
        }
    }
}

// ---------------------------------------------------------------------------
// NMS: one block, 1024 threads (16 waves). Fast path (M <= 8192): boxes in
// LDS, scores in registers (static indices only). Per iteration: register
// argmax -> wave butterfly -> 16 partials -> wave0 reduce -> broadcast ->
// register-local suppression. 2 barriers/iter.
// ---------------------------------------------------------------------------
__global__ __launch_bounds__(NMS_THREADS) void nms_kernel(
    const float4* __restrict__ pbox, float* __restrict__ pscore,
    const float* __restrict__ pcls, const int* __restrict__ counter,
    int capacity, float* __restrict__ out)
{
    __shared__ __align__(16) float4 lbox[NMS_LBOX];
    __shared__ float psc[16];
    __shared__ int   pix[16];
    __shared__ int   swi;

    int M = *counter;
    if (M > capacity) M = capacity;
    const int tid  = (int)threadIdx.x;
    const int lane = tid & 63;
    const int wid  = tid >> 6;

    if (M <= NMS_LBOX) {
        // -------- fast path: boxes LDS-resident, scores in registers --------
        float sc[KA];
#pragma unroll
        for (int k = 0; k < KA; ++k) {
            int j = tid + (k << 10);
            sc[k] = (j < M) ? pscore[j] : -INFINITY;
            if (j < M) lbox[j] = pbox[j];
        }
        __syncthreads();

        for (int it = 0; it < MAXOUT; ++it) {
            float bs = -INFINITY; int bi = -1;
#pragma unroll
            for (int k = 0; k < KA; ++k) {          // ascending j => first-max
                if (sc[k] > bs) { bs = sc[k]; bi = tid + (k << 10); }
            }
#pragma unroll
            for (int off = 32; off; off >>= 1) {
                float os = __shfl_xor(bs, off);
                int   oi = __shfl_xor(bi, off);
                if (os > bs || (os == bs && oi != -1 && (bi == -1 || oi < bi))) {
                    bs = os; bi = oi;
                }
            }
            if (lane == 0) { psc[wid] = bs; pix[wid] = bi; }
            __syncthreads();

            if (wid == 0 && lane < 16) {
                bs = psc[lane]; bi = pix[lane];
#pragma unroll
                for (int off = 8; off; off >>= 1) { // stays within lanes 0..15
                    float os = __shfl_xor(bs, off);
                    int   oi = __shfl_xor(bi, off);
                    if (os > bs || (os == bs && oi != -1 && (bi == -1 || oi < bi))) {
                        bs = os; bi = oi;
                    }
                }
                if (lane == 0) {
                    bool valid = (bi >= 0) && (bs > NEGV * 0.5f);
                    swi = valid ? bi : -1;
                    if (valid) {
                        float4 b = lbox[bi];
                        out[it*6+0] = b.x; out[it*6+1] = b.y;
                        out[it*6+2] = b.z; out[it*6+3] = b.w;
                        out[it*6+4] = bs;  out[it*6+5] = pcls[bi];
                    } else {
                        out[it*6+0] = 0.f; out[it*6+1] = 0.f; out[it*6+2] = 0.f;
                        out[it*6+3] = 0.f; out[it*6+4] = 0.f; out[it*6+5] = 0.f;
                    }
                }
            }
            __syncthreads();

            int wi = swi;
            if (wi >= 0) {
                float4 wb = lbox[wi];
                float a1 = fmaxf(wb.z - wb.x, 0.f) * fmaxf(wb.w - wb.y, 0.f);
#pragma unroll
                for (int k = 0; k < KA; ++k) {      // static reg indices only
                    int j = tid + (k << 10);
                    if (j == wi) sc[k] = NEGV;      // reference kills selected
                    if (j < M) {
                        float4 bj = lbox[j];
                        float ty = fmaxf(wb.x, bj.x);
                        float tx = fmaxf(wb.y, bj.y);
                        float by = fminf(wb.z, bj.z);
                        float bx = fminf(wb.w, bj.w);
                        float inter = fmaxf(by - ty, 0.f) * fmaxf(bx - tx, 0.f);
                        float a2 = fmaxf(bj.z - bj.x, 0.f) * fmaxf(bj.w - bj.y, 0.f);
                        float iou = inter / (a1 + a2 - inter + 1e-9f);
                        if (iou > IOU_T) sc[k] = NEGV;
                    }
                }
            }
        }
    } else {
        // -------- fallback: everything in global (L2-resident), 16 waves ----
        for (int it = 0; it < MAXOUT; ++it) {
            float bs = -INFINITY; int bi = -1;
            for (int j = tid; j < M; j += NMS_THREADS) {
                float s = pscore[j];
                if (s > bs) { bs = s; bi = j; }
            }
#pragma unroll
            for (int off = 32; off; off >>= 1) {
                float os = __shfl_xor(bs, off);
                int   oi = __shfl_xor(bi, off);
                if (os > bs || (os == bs && oi != -1 && (bi == -1 || oi < bi))) {
                    bs = os; bi = oi;
                }
            }
            if (lane == 0) { psc[wid] = bs; pix[wid] = bi; }
            __syncthreads();
            if (wid == 0 && lane < 16) {
                bs = psc[lane]; bi = pix[lane];
#pragma unroll
                for (int off = 8; off; off >>= 1) {
                    float os = __shfl_xor(bs, off);
                    int   oi = __shfl_xor(bi, off);
                    if (os > bs || (os == bs && oi != -1 && (bi == -1 || oi < bi))) {
                        bs = os; bi = oi;
                    }
                }
                if (lane == 0) {
                    bool valid = (bi >= 0) && (bs > NEGV * 0.5f);
                    swi = valid ? bi : -1;
                    if (valid) {
                        float4 b = pbox[bi];
                        out[it*6+0] = b.x; out[it*6+1] = b.y;
                        out[it*6+2] = b.z; out[it*6+3] = b.w;
                        out[it*6+4] = bs;  out[it*6+5] = pcls[bi];
                        pscore[bi] = NEGV;
                    } else {
                        out[it*6+0] = 0.f; out[it*6+1] = 0.f; out[it*6+2] = 0.f;
                        out[it*6+3] = 0.f; out[it*6+4] = 0.f; out[it*6+5] = 0.f;
                    }
                }
            }
            __syncthreads();
            int wi = swi;
            if (wi >= 0) {
                float4 wb = pbox[wi];
                float a1 = fmaxf(wb.z - wb.x, 0.f) * fmaxf(wb.w - wb.y, 0.f);
                for (int j = tid; j < M; j += NMS_THREADS) {
                    float4 bj = pbox[j];
                    float ty = fmaxf(wb.x, bj.x);
                    float tx = fmaxf(wb.y, bj.y);
                    float by = fminf(wb.z, bj.z);
                    float bx = fminf(wb.w, bj.w);
                    float inter = fmaxf(by - ty, 0.f) * fmaxf(bx - tx, 0.f);
                    float a2 = fmaxf(bj.z - bj.x, 0.f) * fmaxf(bj.w - bj.y, 0.f);
                    float iou = inter / (a1 + a2 - inter + 1e-9f);
                    if (iou > IOU_T) pscore[j] = NEGV;
                }
            }
            __syncthreads();
        }
    }
}

extern "C" void kernel_launch(void* const* d_in, const int* in_sizes, int n_in,
                              void* d_out, int out_size, void* d_ws, size_t ws_size,
                              hipStream_t stream) {
    (void)n_in; (void)out_size;
    const float* preds   = (const float*)d_in[0];
    const float* anchors = (const float*)d_in[1];
    float* out = (float*)d_out;

    int N = in_sizes[0] / CH;   // 216,320 boxes

    // Workspace: [0,64) counter; pbox float4[cap]; pscore[cap]; pcls[cap].
    char* ws = (char*)d_ws;
    int* counter = (int*)ws;
    size_t avail = (ws_size > 64) ? (ws_size - 64) : 0;
    long long cap = (long long)(avail / (sizeof(float4) + 2 * sizeof(float)));
    if (cap > N) cap = N;
    if (cap < 0) cap = 0;
    int capacity = (int)cap;

    float4* pbox  = (float4*)(ws + 64);
    float* pscore = (float*)(pbox + capacity);
    float* pcls   = pscore + capacity;

    hipMemsetAsync(counter, 0, sizeof(int), stream);

    int nTiles = (N + BPB - 1) / BPB;   // 3380
    decode_kernel<<<nTiles, DEC_THREADS, 0, stream>>>(
        preds, anchors, pbox, pscore, pcls, counter, N, capacity);
    nms_kernel<<<1, NMS_THREADS, 0, stream>>>(
        pbox, pscore, pcls, counter, capacity, out);
}